// Round 7
// baseline (2373.862 us; speedup 1.0000x reference)
//
#include <hip/hip_runtime.h>
#include <hip/hip_bf16.h>
#include <cmath>

#define NN 100000
#define IND 512
#define HID 64
#define NC  40
#define BWN 128                      // nodes per bucket
#define NBKT ((NN + BWN - 1) / BWN)  // 782
#define NBIN_BLOCKS 100

typedef unsigned int uint32;
typedef unsigned short ushort;
using short8 = __attribute__((ext_vector_type(8))) short;
using f32x4  = __attribute__((ext_vector_type(4))) float;

__device__ inline float bf_lo(uint32 u) { return __uint_as_float(u << 16); }
__device__ inline float bf_hi(uint32 u) { return __uint_as_float(u & 0xFFFF0000u); }
__device__ inline uint32 f2bf(float f) {
    uint32 u = __float_as_uint(f);
    return (u + 0x7FFFu + ((u >> 16) & 1u)) >> 16;  // RNE
}
__device__ inline uint32 pack2bf(float a, float b) { return f2bf(a) | (f2bf(b) << 16); }

// ---------------- bucket binning (dst-major, 128-node buckets) ----------------

__global__ __launch_bounds__(256) void zero_kernel(int* __restrict__ ghist, int n) {
    int i = blockIdx.x * blockDim.x + threadIdx.x;
    if (i < n) ghist[i] = 0;
}

__global__ __launch_bounds__(256) void bhist_kernel(const int* __restrict__ dst,
                                                    int* __restrict__ ghist, int E) {
    __shared__ int hist[NBKT];
    int t = threadIdx.x;
    for (int i = t; i < NBKT; i += 256) hist[i] = 0;
    __syncthreads();
    for (int e = blockIdx.x * 256 + t; e < E; e += gridDim.x * 256)
        atomicAdd(&hist[dst[e] >> 7], 1);
    __syncthreads();
    for (int i = t; i < NBKT; i += 256)
        if (hist[i]) atomicAdd(&ghist[i], hist[i]);
}

__global__ __launch_bounds__(1024) void bscan_kernel(const int* __restrict__ ghist,
                                                     int* __restrict__ bbase,
                                                     int* __restrict__ gcursor) {
    __shared__ int sh[1024];
    int t = threadIdx.x;
    int v = (t < NBKT) ? ghist[t] : 0;
    sh[t] = v;
    __syncthreads();
    for (int off = 1; off < 1024; off <<= 1) {
        int u = (t >= off) ? sh[t - off] : 0;
        __syncthreads();
        sh[t] += u;
        __syncthreads();
    }
    int ex = sh[t] - v;
    if (t < NBKT) { bbase[t] = ex; gcursor[t] = ex; }
    if (t == NBKT - 1) bbase[NBKT] = ex + v;
}

__global__ __launch_bounds__(512) void bin_kernel(const int* __restrict__ src,
                                                  const int* __restrict__ dst,
                                                  int* __restrict__ gcursor,
                                                  int* __restrict__ packed, int E) {
    __shared__ int hist[NBKT], base[NBKT], cur[NBKT];
    int b = blockIdx.x, t = threadIdx.x;
    int epb = (E + gridDim.x - 1) / gridDim.x;
    int lo = b * epb;
    int hi = lo + epb; if (hi > E) hi = E;
    for (int i = t; i < NBKT; i += 512) { hist[i] = 0; cur[i] = 0; }
    __syncthreads();
    for (int e = lo + t; e < hi; e += 512) atomicAdd(&hist[dst[e] >> 7], 1);
    __syncthreads();
    for (int i = t; i < NBKT; i += 512)
        if (hist[i]) base[i] = atomicAdd(&gcursor[i], hist[i]);
    __syncthreads();
    for (int e = lo + t; e < hi; e += 512) {
        int d = dst[e], s = src[e];
        int bk = d >> 7;
        int pos = base[bk] + atomicAdd(&cur[bk], 1);
        packed[pos] = ((d & 127) << 17) | s;
    }
}

// per-bucket degree -> dinv (no CSR scatter needed anymore)
__global__ __launch_bounds__(256) void deg_bucket(const int* __restrict__ packed,
                                                  const int* __restrict__ bbase,
                                                  float* __restrict__ dinv) {
    __shared__ int hist[BWN];
    int b = blockIdx.x, t = threadIdx.x;
    if (t < BWN) hist[t] = 0;
    __syncthreads();
    int ebeg = bbase[b], eend = bbase[b + 1];
    for (int e = ebeg + t; e < eend; e += 256) atomicAdd(&hist[(packed[e] >> 17) & 127], 1);
    __syncthreads();
    int n = b * BWN + t;
    if (t < BWN && n < NN) dinv[n] = rsqrtf((float)(hist[t] + 1));
}

// ---------------- W1 transpose + bf16 convert ----------------

__global__ __launch_bounds__(256) void w1t_kernel(const float* __restrict__ W1,
                                                  ushort* __restrict__ w1t) {
    int id = blockIdx.x * blockDim.x + threadIdx.x;
    if (id >= IND * HID) return;
    int n = id & 63, k = id >> 6;
    w1t[(size_t)n * IND + k] = (ushort)f2bf(W1[(size_t)k * HID + n]);
}

// ---------------- Layer 1 GEMM (MFMA bf16): hs = bf16((x @ W1) * dinv[row]) ----------------

__global__ __launch_bounds__(256) void gemm1_mfma(const float* __restrict__ x,
                                                  const ushort* __restrict__ w1t,
                                                  const float* __restrict__ dinv,
                                                  ushort* __restrict__ hs, int M) {
    __shared__ ushort As[64 * 64];
    __shared__ ushort Bs[64 * 64];
    char* Ab = (char*)As;
    char* Bb = (char*)Bs;

    int t = threadIdx.x;
    int row0 = blockIdx.x * 64;

    int srow = t >> 2;
    int klane = t & 3;
    int grow = row0 + srow; if (grow > M - 1) grow = M - 1;
    const float* xrow = x + (size_t)grow * IND;
    const char* wrow = (const char*)(w1t + (size_t)srow * IND);
    int swrow = srow * 128;
    int swx = (srow & 7) << 4;

    int l = t & 63;
    int w = t >> 6;
    int lr = l & 15;
    int lk = (l >> 4) * 16;
    int arow_b = (w * 16 + lr) * 128;
    int aswz = ((w * 16 + lr) & 7) << 4;

    f32x4 acc[4] = {};

    for (int k0 = 0; k0 < IND; k0 += 64) {
#pragma unroll
        for (int i = 0; i < 4; ++i) {
            float4 v = *(const float4*)(xrow + k0 + i * 16 + klane * 4);
            uint2 pkd;
            pkd.x = pack2bf(v.x, v.y);
            pkd.y = pack2bf(v.z, v.w);
            int kb = i * 32 + klane * 8;
            *(uint2*)(Ab + swrow + (kb ^ swx)) = pkd;
            uint2 wv = *(const uint2*)(wrow + k0 * 2 + kb);
            *(uint2*)(Bb + swrow + (kb ^ swx)) = wv;
        }
        __syncthreads();

        short8 a0 = *(const short8*)(Ab + arow_b + ((0 + lk) ^ aswz));
        short8 a1 = *(const short8*)(Ab + arow_b + ((64 + lk) ^ aswz));
#pragma unroll
        for (int ns = 0; ns < 4; ++ns) {
            int brow = ns * 16 + lr;
            int bswz = (brow & 7) << 4;
            short8 b0 = *(const short8*)(Bb + brow * 128 + ((0 + lk) ^ bswz));
            short8 b1 = *(const short8*)(Bb + brow * 128 + ((64 + lk) ^ bswz));
            acc[ns] = __builtin_amdgcn_mfma_f32_16x16x32_bf16(a0, b0, acc[ns], 0, 0, 0);
            acc[ns] = __builtin_amdgcn_mfma_f32_16x16x32_bf16(a1, b1, acc[ns], 0, 0, 0);
        }
        __syncthreads();
    }

    int rbase = row0 + w * 16 + (l >> 4) * 4;
    float dv[4];
#pragma unroll
    for (int j = 0; j < 4; ++j) dv[j] = (rbase + j < M) ? dinv[rbase + j] : 0.f;
#pragma unroll
    for (int ns = 0; ns < 4; ++ns) {
        int col = ns * 16 + lr;
#pragma unroll
        for (int j = 0; j < 4; ++j) {
            int row = rbase + j;
            if (row < M) hs[(size_t)row * HID + col] = (ushort)f2bf(acc[ns][j] * dv[j]);
        }
    }
}

// ---------------- agg1: bucket-local LDS accumulation ----------------
// one block per 128-node bucket; LDS f32 accum [128][64] = 32 KB.

__global__ __launch_bounds__(256) void agg1_bucket(const uint32* __restrict__ hs,
                                                   const int* __restrict__ packed,
                                                   const int* __restrict__ bbase,
                                                   const float* __restrict__ dinv,
                                                   const float* __restrict__ b1,
                                                   uint32* __restrict__ h1) {
    __shared__ float acc[BWN][64];
    int b = blockIdx.x, t = threadIdx.x;
    float4* accv = (float4*)&acc[0][0];
    for (int i = t; i < BWN * 16; i += 256) accv[i] = float4{0.f, 0.f, 0.f, 0.f};
    __syncthreads();

    int ebeg = bbase[b], eend = bbase[b + 1];
    int hw = t >> 5, l = t & 31;
    for (int e0 = ebeg + hw * 4; e0 < eend; e0 += 32) {
        int ne = eend - e0; if (ne > 4) ne = 4;
        int pk[4]; uint32 uu[4];
#pragma unroll
        for (int j = 0; j < 4; ++j) {
            if (j < ne) {
                pk[j] = packed[e0 + j];
                uu[j] = hs[(size_t)(pk[j] & 0x1FFFF) * 32 + l];
            }
        }
#pragma unroll
        for (int j = 0; j < 4; ++j) {
            if (j < ne) {
                int dl = (pk[j] >> 17) & 127;
                atomicAdd(&acc[dl][2 * l], bf_lo(uu[j]));
                atomicAdd(&acc[dl][2 * l + 1], bf_hi(uu[j]));
            }
        }
    }
    __syncthreads();

    int nlo = b * BWN;
    int ncnt = NN - nlo; if (ncnt > BWN) ncnt = BWN;
    float2 bb = *(const float2*)(b1 + 2 * l);
    for (int r = hw; r < ncnt; r += 8) {
        int n = nlo + r;
        uint32 u = hs[(size_t)n * 32 + l];  // self (dinv-scaled)
        float d = dinv[n];
        float2 av = *(float2*)&acc[r][2 * l];
        float v0 = (av.x + bf_lo(u)) * d + bb.x;
        float v1 = (av.y + bf_hi(u)) * d + bb.y;
        v0 = v0 > 0.f ? v0 : 0.f;
        v1 = v1 > 0.f ? v1 : 0.f;
        __builtin_nontemporal_store(pack2bf(v0, v1), &h1[(size_t)n * 32 + l]);
    }
}

// ---------------- Layer 2 GEMM: h2b(bf16) = (h1(bf16) @ W2) * dinv ----------------

__global__ __launch_bounds__(256) void gemm2_kernel(const uint32* __restrict__ h1,
                                                    const float* __restrict__ W2,
                                                    const float* __restrict__ dinv,
                                                    ushort* __restrict__ h2b, int M) {
    __shared__ float hsld[64][68];
    __shared__ float wls[64 * 40];
    int tid = threadIdx.x;
    int row0 = blockIdx.x * 64;

    int r = tid >> 2;
    int q = tid & 3;
    int grow = row0 + r; if (grow > M - 1) grow = M - 1;
    const uint4* srcp = (const uint4*)(h1 + (size_t)grow * 32);
    uint4 q0 = srcp[q * 2];
    uint4 q1 = srcp[q * 2 + 1];
    uint32 wv[8] = {q0.x, q0.y, q0.z, q0.w, q1.x, q1.y, q1.z, q1.w};
#pragma unroll
    for (int jw = 0; jw < 8; ++jw) {
        hsld[r][q * 16 + 2 * jw]     = bf_lo(wv[jw]);
        hsld[r][q * 16 + 2 * jw + 1] = bf_hi(wv[jw]);
    }
    for (int idx = tid; idx < HID * NC; idx += 256) wls[idx] = W2[idx];
    __syncthreads();

    for (int o = tid; o < 64 * NC; o += 256) {
        int rr = o / NC;
        int c = o - rr * NC;
        float s = 0.f;
#pragma unroll
        for (int k4 = 0; k4 < 16; ++k4) {
            float4 hv = *(float4*)&hsld[rr][k4 * 4];
            s += hv.x * wls[(k4 * 4 + 0) * NC + c];
            s += hv.y * wls[(k4 * 4 + 1) * NC + c];
            s += hv.z * wls[(k4 * 4 + 2) * NC + c];
            s += hv.w * wls[(k4 * 4 + 3) * NC + c];
        }
        int row = row0 + rr;
        if (row < M) h2b[(size_t)row * NC + c] = (ushort)f2bf(s * dinv[row]);
    }
}

// ---------------- agg2: bucket-local LDS accumulation + log_softmax ----------------
// one block per bucket; LDS f32 accum [128][40] = 20 KB.

__global__ __launch_bounds__(256) void agg2_bucket(const uint32* __restrict__ h2b,
                                                   const int* __restrict__ packed,
                                                   const int* __restrict__ bbase,
                                                   const float* __restrict__ dinv,
                                                   const float* __restrict__ b2,
                                                   float* __restrict__ out) {
    __shared__ float acc[BWN][40];
    int b = blockIdx.x, t = threadIdx.x;
    float* accf = &acc[0][0];
    for (int i = t; i < BWN * 40; i += 256) accf[i] = 0.f;
    __syncthreads();

    int ebeg = bbase[b], eend = bbase[b + 1];
    int hw = t >> 5, l = t & 31;
    bool act = l < 20;
    for (int e0 = ebeg + hw * 4; e0 < eend; e0 += 32) {
        int ne = eend - e0; if (ne > 4) ne = 4;
        int pk[4]; uint32 uu[4];
#pragma unroll
        for (int j = 0; j < 4; ++j) {
            if (j < ne) {
                pk[j] = packed[e0 + j];
                if (act) uu[j] = h2b[(size_t)(pk[j] & 0x1FFFF) * 20 + l];
            }
        }
#pragma unroll
        for (int j = 0; j < 4; ++j) {
            if (j < ne && act) {
                int dl = (pk[j] >> 17) & 127;
                atomicAdd(&acc[dl][2 * l], bf_lo(uu[j]));
                atomicAdd(&acc[dl][2 * l + 1], bf_hi(uu[j]));
            }
        }
    }
    __syncthreads();

    int nlo = b * BWN;
    int ncnt = NN - nlo; if (ncnt > BWN) ncnt = BWN;
    float2 bb = act ? *(const float2*)(b2 + 2 * l) : float2{0.f, 0.f};
    for (int r = hw; r < ncnt; r += 8) {
        int n = nlo + r;
        float v0 = -INFINITY, v1 = -INFINITY;
        if (act) {
            uint32 u = h2b[(size_t)n * 20 + l];  // self
            float d = dinv[n];
            float2 av = *(float2*)&acc[r][2 * l];
            v0 = (av.x + bf_lo(u)) * d + bb.x;
            v1 = (av.y + bf_hi(u)) * d + bb.y;
        }
        float m = fmaxf(v0, v1);
#pragma unroll
        for (int off = 16; off; off >>= 1) m = fmaxf(m, __shfl_xor(m, off));
        float s = act ? (expf(v0 - m) + expf(v1 - m)) : 0.f;
#pragma unroll
        for (int off = 16; off; off >>= 1) s += __shfl_xor(s, off);
        if (act) {
            float ls = logf(s);
            __builtin_nontemporal_store(v0 - m - ls, &out[(size_t)n * NC + 2 * l]);
            __builtin_nontemporal_store(v1 - m - ls, &out[(size_t)n * NC + 2 * l + 1]);
        }
    }
}

// ---------------- launch ----------------

extern "C" void kernel_launch(void* const* d_in, const int* in_sizes, int n_in,
                              void* d_out, int out_size, void* d_ws, size_t ws_size,
                              hipStream_t stream) {
    const float* x  = (const float*)d_in[0];
    const int* ei   = (const int*)d_in[1];
    const float* W1 = (const float*)d_in[2];
    const float* b1 = (const float*)d_in[3];
    const float* W2 = (const float*)d_in[4];
    const float* b2 = (const float*)d_in[5];
    float* out = (float*)d_out;

    const int E = in_sizes[1] / 2;
    const int* src = ei;
    const int* dst = ei + E;

    char* p = (char*)d_ws;
    size_t off = 0;
    auto carve = [&](size_t bytes) {
        void* q = p + off;
        off = (off + bytes + 255) & ~(size_t)255;
        return q;
    };
    int* ghist    = (int*)carve((size_t)NBKT * 4);
    int* bbase    = (int*)carve((size_t)(NBKT + 1) * 4);
    int* gcursor  = (int*)carve((size_t)NBKT * 4);
    float* dinv   = (float*)carve((size_t)NN * 4);
    ushort* w1t   = (ushort*)carve((size_t)IND * HID * 2);      // bf16 W1^T [64][512]
    ushort* hs    = (ushort*)carve((size_t)NN * HID * 2);       // bf16 [NN][64]
    ushort* h2b   = (ushort*)carve((size_t)NN * NC * 2);        // bf16 [NN][40]
    uint32* h1    = (uint32*)carve((size_t)NN * 32 * 4);        // bf16 pairs [NN][32]
    int* packed   = (int*)carve((size_t)E * 4);                 // bucket-sorted edges

    zero_kernel<<<(NBKT + 255) / 256, 256, 0, stream>>>(ghist, NBKT);
    bhist_kernel<<<256, 256, 0, stream>>>(dst, ghist, E);
    bscan_kernel<<<1, 1024, 0, stream>>>(ghist, bbase, gcursor);
    bin_kernel<<<NBIN_BLOCKS, 512, 0, stream>>>(src, dst, gcursor, packed, E);
    deg_bucket<<<NBKT, 256, 0, stream>>>(packed, bbase, dinv);
    w1t_kernel<<<(IND * HID + 255) / 256, 256, 0, stream>>>(W1, w1t);
    gemm1_mfma<<<(NN + 63) / 64, 256, 0, stream>>>(x, w1t, dinv, hs, NN);
    agg1_bucket<<<NBKT, 256, 0, stream>>>((const uint32*)hs, packed, bbase, dinv, b1, h1);
    gemm2_kernel<<<(NN + 63) / 64, 256, 0, stream>>>(h1, W2, dinv, h2b, NN);
    agg2_bucket<<<NBKT, 256, 0, stream>>>((const uint32*)h2b, packed, bbase, dinv, b2, out);
}

// Round 8
// 339.273 us; speedup vs baseline: 6.9969x; 6.9969x over previous
//
#include <hip/hip_runtime.h>
#include <hip/hip_bf16.h>
#include <cmath>

#define NN 100000
#define IND 512
#define HID 64
#define NC  40
#define BWN 256                      // nodes per bucket
#define NBKT ((NN + BWN - 1) / BWN)  // 391
#define NBIN_BLOCKS 100

typedef unsigned int uint32;
typedef unsigned short ushort;
using short8 = __attribute__((ext_vector_type(8))) short;
using f32x4  = __attribute__((ext_vector_type(4))) float;

__device__ inline float bf_lo(uint32 u) { return __uint_as_float(u << 16); }
__device__ inline float bf_hi(uint32 u) { return __uint_as_float(u & 0xFFFF0000u); }
__device__ inline uint32 f2bf(float f) {
    uint32 u = __float_as_uint(f);
    return (u + 0x7FFFu + ((u >> 16) & 1u)) >> 16;  // RNE
}
__device__ inline uint32 pack2bf(float a, float b) { return f2bf(a) | (f2bf(b) << 16); }

// ---------------- CSR build: two-level bucket sort (round-6 structure) ----------------

__global__ __launch_bounds__(256) void zero_kernel(int* __restrict__ ghist, int n) {
    int i = blockIdx.x * blockDim.x + threadIdx.x;
    if (i < n) ghist[i] = 0;
}

__global__ __launch_bounds__(256) void bhist_kernel(const int* __restrict__ dst,
                                                    int* __restrict__ ghist, int E) {
    __shared__ int hist[NBKT];
    int t = threadIdx.x;
    for (int i = t; i < NBKT; i += 256) hist[i] = 0;
    __syncthreads();
    for (int e = blockIdx.x * 256 + t; e < E; e += gridDim.x * 256)
        atomicAdd(&hist[dst[e] >> 8], 1);
    __syncthreads();
    for (int i = t; i < NBKT; i += 256)
        if (hist[i]) atomicAdd(&ghist[i], hist[i]);
}

__global__ __launch_bounds__(512) void bscan_kernel(const int* __restrict__ ghist,
                                                    int* __restrict__ bbase,
                                                    int* __restrict__ gcursor) {
    __shared__ int sh[512];
    int t = threadIdx.x;
    int v = (t < NBKT) ? ghist[t] : 0;
    sh[t] = v;
    __syncthreads();
    for (int off = 1; off < 512; off <<= 1) {
        int u = (t >= off) ? sh[t - off] : 0;
        __syncthreads();
        sh[t] += u;
        __syncthreads();
    }
    int ex = sh[t] - v;
    if (t < NBKT) { bbase[t] = ex; gcursor[t] = ex; }
    if (t == NBKT - 1) bbase[NBKT] = ex + v;
}

__global__ __launch_bounds__(512) void bin_kernel(const int* __restrict__ src,
                                                  const int* __restrict__ dst,
                                                  int* __restrict__ gcursor,
                                                  int* __restrict__ packed, int E) {
    __shared__ int hist[NBKT], base[NBKT], cur[NBKT];
    int b = blockIdx.x, t = threadIdx.x;
    int epb = (E + gridDim.x - 1) / gridDim.x;
    int lo = b * epb;
    int hi = lo + epb; if (hi > E) hi = E;
    for (int i = t; i < NBKT; i += 512) { hist[i] = 0; cur[i] = 0; }
    __syncthreads();
    for (int e = lo + t; e < hi; e += 512) atomicAdd(&hist[dst[e] >> 8], 1);
    __syncthreads();
    for (int i = t; i < NBKT; i += 512)
        if (hist[i]) base[i] = atomicAdd(&gcursor[i], hist[i]);
    __syncthreads();
    for (int e = lo + t; e < hi; e += 512) {
        int d = dst[e], s = src[e];
        int bk = d >> 8;
        int pos = base[bk] + atomicAdd(&cur[bk], 1);
        packed[pos] = ((d & 255) << 17) | s;
    }
}

__global__ __launch_bounds__(256) void csr_bucket_kernel(const int* __restrict__ packed,
                                                         const int* __restrict__ bbase,
                                                         int* __restrict__ rowptr,
                                                         int* __restrict__ colx,
                                                         float* __restrict__ dinv, int E) {
    __shared__ int hist[BWN], pfx[BWN], cur[BWN];
    int b = blockIdx.x, t = threadIdx.x;
    int nlo = b * BWN;
    int ncnt = NN - nlo; if (ncnt > BWN) ncnt = BWN;
    int ebeg = bbase[b], eend = bbase[b + 1];
    hist[t] = 0;
    __syncthreads();
    for (int e = ebeg + t; e < eend; e += 256) atomicAdd(&hist[packed[e] >> 17], 1);
    __syncthreads();
    int h = hist[t];
    pfx[t] = h;
    __syncthreads();
    for (int off = 1; off < 256; off <<= 1) {
        int u = (t >= off) ? pfx[t - off] : 0;
        __syncthreads();
        pfx[t] += u;
        __syncthreads();
    }
    int excl = pfx[t] - h;
    cur[t] = excl;
    int g = nlo + t;
    if (t < ncnt) {
        rowptr[g] = ebeg + excl;
        dinv[g] = rsqrtf((float)(h + 1));  // +1 self-loop
    }
    if (b == 0 && t == 0) rowptr[NN] = E;
    __syncthreads();
    for (int e = ebeg + t; e < eend; e += 256) {
        int p = packed[e];
        int dl = p >> 17;
        int s = p & 0x1FFFF;
        int pos = ebeg + atomicAdd(&cur[dl], 1);
        colx[pos] = s;
    }
}

// ---------------- weight transposes: W1T[64][512], W2T[48][64] (bf16, zero-padded) ----------------

__global__ __launch_bounds__(256) void wt_kernel(const float* __restrict__ W1,
                                                 const float* __restrict__ W2,
                                                 ushort* __restrict__ w1t,
                                                 ushort* __restrict__ w2t) {
    int id = blockIdx.x * blockDim.x + threadIdx.x;
    if (id < IND * HID) {
        int n = id & 63, k = id >> 6;
        w1t[(size_t)n * IND + k] = (ushort)f2bf(W1[(size_t)k * HID + n]);
    } else if (id < IND * HID + 48 * HID) {
        int id2 = id - IND * HID;
        int n = id2 >> 6, k = id2 & 63;
        w2t[id2] = (n < NC) ? (ushort)f2bf(W2[(size_t)k * NC + n]) : (ushort)0;
    }
}

// ---------------- Layer 1 GEMM (MFMA bf16, reg-prefetch pipeline) ----------------
// hs = bf16((x @ W1) * dinv[row]); 4 waves, tile 64x64, BK=64, XOR-swizzled LDS.

__global__ __launch_bounds__(256) void gemm1_mfma(const float* __restrict__ x,
                                                  const ushort* __restrict__ w1t,
                                                  const float* __restrict__ dinv,
                                                  ushort* __restrict__ hs, int M) {
    __shared__ ushort As[64 * 64];
    __shared__ ushort Bs[64 * 64];
    char* Ab = (char*)As;
    char* Bb = (char*)Bs;

    int t = threadIdx.x;
    int row0 = blockIdx.x * 64;

    int srow = t >> 2;
    int klane = t & 3;
    int grow = row0 + srow; if (grow > M - 1) grow = M - 1;
    const float* xrow = x + (size_t)grow * IND;
    const char* wrow = (const char*)(w1t + (size_t)srow * IND);
    int swrow = srow * 128;
    int swx = (srow & 7) << 4;

    int l = t & 63;
    int w = t >> 6;
    int lr = l & 15;
    int lk = (l >> 4) * 16;
    int arow_b = (w * 16 + lr) * 128;
    int aswz = ((w * 16 + lr) & 7) << 4;

    f32x4 acc[4] = {};

    // preload k0=0 tile into regs
    float4 rx[4]; uint2 rw[4];
#pragma unroll
    for (int i = 0; i < 4; ++i) {
        rx[i] = *(const float4*)(xrow + i * 16 + klane * 4);
        rw[i] = *(const uint2*)(wrow + i * 32 + klane * 8);
    }

    for (int k0 = 0; k0 < IND; k0 += 64) {
#pragma unroll
        for (int i = 0; i < 4; ++i) {
            int kb = i * 32 + klane * 8;
            uint2 pkd;
            pkd.x = pack2bf(rx[i].x, rx[i].y);
            pkd.y = pack2bf(rx[i].z, rx[i].w);
            *(uint2*)(Ab + swrow + (kb ^ swx)) = pkd;
            *(uint2*)(Bb + swrow + (kb ^ swx)) = rw[i];
        }
        __syncthreads();

        if (k0 + 64 < IND) {  // prefetch next tile; completes under MFMA
#pragma unroll
            for (int i = 0; i < 4; ++i) {
                rx[i] = *(const float4*)(xrow + k0 + 64 + i * 16 + klane * 4);
                rw[i] = *(const uint2*)(wrow + (k0 + 64) * 2 + i * 32 + klane * 8);
            }
        }

        short8 a0 = *(const short8*)(Ab + arow_b + ((0 + lk) ^ aswz));
        short8 a1 = *(const short8*)(Ab + arow_b + ((64 + lk) ^ aswz));
#pragma unroll
        for (int ns = 0; ns < 4; ++ns) {
            int brow = ns * 16 + lr;
            int bswz = (brow & 7) << 4;
            short8 b0 = *(const short8*)(Bb + brow * 128 + ((0 + lk) ^ bswz));
            short8 b1 = *(const short8*)(Bb + brow * 128 + ((64 + lk) ^ bswz));
            acc[ns] = __builtin_amdgcn_mfma_f32_16x16x32_bf16(a0, b0, acc[ns], 0, 0, 0);
            acc[ns] = __builtin_amdgcn_mfma_f32_16x16x32_bf16(a1, b1, acc[ns], 0, 0, 0);
        }
        __syncthreads();
    }

    int rbase = row0 + w * 16 + (l >> 4) * 4;
    float dv[4];
#pragma unroll
    for (int j = 0; j < 4; ++j) dv[j] = (rbase + j < M) ? dinv[rbase + j] : 0.f;
#pragma unroll
    for (int ns = 0; ns < 4; ++ns) {
        int col = ns * 16 + lr;
#pragma unroll
        for (int j = 0; j < 4; ++j) {
            int row = rbase + j;
            if (row < M) hs[(size_t)row * HID + col] = (ushort)f2bf(acc[ns][j] * dv[j]);
        }
    }
}

// ---------------- agg1: half-wave per node, bf16 gather, nt colx, bf16 h1 out ----------------

__global__ __launch_bounds__(256) void agg1_kernel(const uint32* __restrict__ hs,
                                                   const int* __restrict__ rowptr,
                                                   const int* __restrict__ colx,
                                                   const float* __restrict__ dinv,
                                                   const float* __restrict__ b1,
                                                   uint32* __restrict__ h1) {
    int node = (blockIdx.x * blockDim.x + threadIdx.x) >> 5;
    int l = threadIdx.x & 31;
    if (node >= NN) return;
    int beg = rowptr[node], end = rowptr[node + 1];
    uint32 u = hs[(size_t)node * 32 + l];  // self (already dinv-scaled)
    float a0 = bf_lo(u), a1 = bf_hi(u);
    int e = beg;
    int n8 = beg + ((end - beg) & ~7);
    for (; e < n8; e += 8) {
        int c[8];
#pragma unroll
        for (int j = 0; j < 8; ++j) c[j] = __builtin_nontemporal_load(&colx[e + j]);
        uint32 uu[8];
#pragma unroll
        for (int j = 0; j < 8; ++j) uu[j] = hs[(size_t)c[j] * 32 + l];
#pragma unroll
        for (int j = 0; j < 8; ++j) { a0 += bf_lo(uu[j]); a1 += bf_hi(uu[j]); }
    }
    for (; e < end; ++e) {
        uint32 ue = hs[(size_t)__builtin_nontemporal_load(&colx[e]) * 32 + l];
        a0 += bf_lo(ue); a1 += bf_hi(ue);
    }
    float d = dinv[node];
    float2 bb = *(const float2*)(b1 + 2 * l);
    float v0 = a0 * d + bb.x;
    float v1 = a1 * d + bb.y;
    v0 = v0 > 0.f ? v0 : 0.f;
    v1 = v1 > 0.f ? v1 : 0.f;
    __builtin_nontemporal_store(pack2bf(v0, v1), &h1[(size_t)node * 32 + l]);
}

// ---------------- Layer 2 GEMM (MFMA, LDS-free): h2b = bf16((h1 @ W2) * dinv) ----------------
// 4 waves x 16 rows; A straight from bf16 h1 rows, B from w2t[48][64] (L2-hot).

__global__ __launch_bounds__(256) void gemm2_mfma(const ushort* __restrict__ h1,
                                                  const ushort* __restrict__ w2t,
                                                  const float* __restrict__ dinv,
                                                  ushort* __restrict__ h2b, int M) {
    int t = threadIdx.x;
    int w = t >> 6, l = t & 63;
    int lr = l & 15, lh = l >> 4;
    int row0 = blockIdx.x * 64 + w * 16;
    int arow = row0 + lr; if (arow > M - 1) arow = M - 1;
    const ushort* hrow = h1 + (size_t)arow * HID;

    f32x4 acc[3] = {};
#pragma unroll
    for (int ks = 0; ks < 2; ++ks) {
        short8 a = *(const short8*)(hrow + ks * 32 + lh * 8);
#pragma unroll
        for (int ns = 0; ns < 3; ++ns) {
            short8 b = *(const short8*)(w2t + (size_t)(ns * 16 + lr) * HID + ks * 32 + lh * 8);
            acc[ns] = __builtin_amdgcn_mfma_f32_16x16x32_bf16(a, b, acc[ns], 0, 0, 0);
        }
    }

    int rbase = row0 + lh * 4;
    float dv[4];
#pragma unroll
    for (int j = 0; j < 4; ++j) dv[j] = (rbase + j < M) ? dinv[rbase + j] : 0.f;
#pragma unroll
    for (int ns = 0; ns < 3; ++ns) {
        int col = ns * 16 + lr;
        if (col < NC) {
#pragma unroll
            for (int j = 0; j < 4; ++j) {
                int row = rbase + j;
                if (row < M) h2b[(size_t)row * NC + col] = (ushort)f2bf(acc[ns][j] * dv[j]);
            }
        }
    }
}

// ---------------- agg2 + bias + log_softmax: half-wave per node, nt colx ----------------

__global__ __launch_bounds__(256) void agg2_kernel(const uint32* __restrict__ h2b,
                                                   const int* __restrict__ rowptr,
                                                   const int* __restrict__ colx,
                                                   const float* __restrict__ dinv,
                                                   const float* __restrict__ b2,
                                                   float* __restrict__ out) {
    int node = (blockIdx.x * blockDim.x + threadIdx.x) >> 5;
    int l = threadIdx.x & 31;
    if (node >= NN) return;
    bool act = l < 20;  // 20 bf162 words cover 40 classes
    int beg = rowptr[node], end = rowptr[node + 1];
    float a0 = 0.f, a1 = 0.f;
    if (act) {
        uint32 u = h2b[(size_t)node * 20 + l];
        a0 = bf_lo(u); a1 = bf_hi(u);
    }
    int e = beg;
    int n8 = beg + ((end - beg) & ~7);
    for (; e < n8; e += 8) {
        int c[8];
#pragma unroll
        for (int j = 0; j < 8; ++j) c[j] = __builtin_nontemporal_load(&colx[e + j]);
        if (act) {
            uint32 uu[8];
#pragma unroll
            for (int j = 0; j < 8; ++j) uu[j] = h2b[(size_t)c[j] * 20 + l];
#pragma unroll
            for (int j = 0; j < 8; ++j) { a0 += bf_lo(uu[j]); a1 += bf_hi(uu[j]); }
        }
    }
    for (; e < end; ++e) {
        int c = __builtin_nontemporal_load(&colx[e]);
        if (act) {
            uint32 ue = h2b[(size_t)c * 20 + l];
            a0 += bf_lo(ue); a1 += bf_hi(ue);
        }
    }

    float d = dinv[node];
    float v0 = -INFINITY, v1 = -INFINITY;
    if (act) {
        float2 bb = *(const float2*)(b2 + 2 * l);
        v0 = a0 * d + bb.x;
        v1 = a1 * d + bb.y;
    }
    float m = fmaxf(v0, v1);
#pragma unroll
    for (int off = 16; off; off >>= 1) m = fmaxf(m, __shfl_xor(m, off));
    float s = act ? (expf(v0 - m) + expf(v1 - m)) : 0.f;
#pragma unroll
    for (int off = 16; off; off >>= 1) s += __shfl_xor(s, off);
    if (act) {
        float ls = logf(s);
        __builtin_nontemporal_store(v0 - m - ls, &out[(size_t)node * NC + 2 * l]);
        __builtin_nontemporal_store(v1 - m - ls, &out[(size_t)node * NC + 2 * l + 1]);
    }
}

// ---------------- launch ----------------

extern "C" void kernel_launch(void* const* d_in, const int* in_sizes, int n_in,
                              void* d_out, int out_size, void* d_ws, size_t ws_size,
                              hipStream_t stream) {
    const float* x  = (const float*)d_in[0];
    const int* ei   = (const int*)d_in[1];
    const float* W1 = (const float*)d_in[2];
    const float* b1 = (const float*)d_in[3];
    const float* W2 = (const float*)d_in[4];
    const float* b2 = (const float*)d_in[5];
    float* out = (float*)d_out;

    const int E = in_sizes[1] / 2;
    const int* src = ei;
    const int* dst = ei + E;

    char* p = (char*)d_ws;
    size_t off = 0;
    auto carve = [&](size_t bytes) {
        void* q = p + off;
        off = (off + bytes + 255) & ~(size_t)255;
        return q;
    };
    int* ghist    = (int*)carve((size_t)NBKT * 4);
    int* bbase    = (int*)carve((size_t)(NBKT + 1) * 4);
    int* gcursor  = (int*)carve((size_t)NBKT * 4);
    int* rowptr   = (int*)carve((size_t)(NN + 1) * 4);
    float* dinv   = (float*)carve((size_t)NN * 4);
    int* colx     = (int*)carve((size_t)E * 4);
    ushort* w1t   = (ushort*)carve((size_t)IND * HID * 2);      // bf16 W1^T [64][512]
    ushort* w2t   = (ushort*)carve((size_t)48 * HID * 2);       // bf16 W2^T [48][64], padded
    ushort* hs    = (ushort*)carve((size_t)NN * HID * 2);       // bf16 [NN][64]
    ushort* h2b   = (ushort*)carve((size_t)NN * NC * 2);        // bf16 [NN][40]
    uint32* h1    = (uint32*)carve((size_t)NN * 32 * 4);        // bf16 pairs [NN][32]
    int* packed   = (int*)carve((size_t)E * 4);                 // bin staging

    zero_kernel<<<(NBKT + 255) / 256, 256, 0, stream>>>(ghist, NBKT);
    bhist_kernel<<<256, 256, 0, stream>>>(dst, ghist, E);
    bscan_kernel<<<1, 512, 0, stream>>>(ghist, bbase, gcursor);
    bin_kernel<<<NBIN_BLOCKS, 512, 0, stream>>>(src, dst, gcursor, packed, E);
    csr_bucket_kernel<<<NBKT, 256, 0, stream>>>(packed, bbase, rowptr, colx, dinv, E);
    wt_kernel<<<(IND * HID + 48 * HID + 255) / 256, 256, 0, stream>>>(W1, W2, w1t, w2t);
    gemm1_mfma<<<(NN + 63) / 64, 256, 0, stream>>>(x, w1t, dinv, hs, NN);
    agg1_kernel<<<(NN * 32 + 255) / 256, 256, 0, stream>>>((const uint32*)hs, rowptr, colx, dinv, b1, h1);
    gemm2_mfma<<<(NN + 63) / 64, 256, 0, stream>>>((const ushort*)h1, w2t, dinv, h2b, NN);
    agg2_kernel<<<(NN * 32 + 255) / 256, 256, 0, stream>>>((const uint32*)h2b, rowptr, colx, dinv, b2, out);
}

// Round 9
// 315.964 us; speedup vs baseline: 7.5131x; 1.0738x over previous
//
#include <hip/hip_runtime.h>
#include <hip/hip_bf16.h>
#include <cmath>

#define NN 100000
#define IND 512
#define HID 64
#define NC  40
#define BWN 256                      // nodes per bucket
#define NBKT ((NN + BWN - 1) / BWN)  // 391
#define CAP  12288                   // padded slots per bucket (avg 8184, +50%)
#define NBIN_BLOCKS 200

typedef unsigned int uint32;
typedef unsigned short ushort;
using short8 = __attribute__((ext_vector_type(8))) short;
using f32x4  = __attribute__((ext_vector_type(4))) float;

__device__ inline float bf_lo(uint32 u) { return __uint_as_float(u << 16); }
__device__ inline float bf_hi(uint32 u) { return __uint_as_float(u & 0xFFFF0000u); }
__device__ inline uint32 f2bf(float f) {
    uint32 u = __float_as_uint(f);
    return (u + 0x7FFFu + ((u >> 16) & 1u)) >> 16;  // RNE
}
__device__ inline uint32 pack2bf(float a, float b) { return f2bf(a) | (f2bf(b) << 16); }

// ---------------- wt_init: W1T bf16 transpose + gcursor init ----------------

__global__ __launch_bounds__(256) void wt_init_kernel(const float* __restrict__ W1,
                                                      ushort* __restrict__ w1t,
                                                      int* __restrict__ gcursor) {
    int id = blockIdx.x * blockDim.x + threadIdx.x;
    if (id < IND * HID) {
        int n = id & 63, k = id >> 6;
        w1t[(size_t)n * IND + k] = (ushort)f2bf(W1[(size_t)k * HID + n]);
    }
    if (id < NBKT) gcursor[id] = id * CAP;
}

// ---------------- bin: bucket edges into padded staging ----------------

__global__ __launch_bounds__(512) void bin_kernel(const int* __restrict__ src,
                                                  const int* __restrict__ dst,
                                                  int* __restrict__ gcursor,
                                                  int* __restrict__ packed, int E) {
    __shared__ int hist[NBKT], base[NBKT], cur[NBKT];
    int b = blockIdx.x, t = threadIdx.x;
    int epb = (E + gridDim.x - 1) / gridDim.x;
    int lo = b * epb;
    int hi = lo + epb; if (hi > E) hi = E;
    for (int i = t; i < NBKT; i += 512) { hist[i] = 0; cur[i] = 0; }
    __syncthreads();
    for (int e = lo + t; e < hi; e += 512) atomicAdd(&hist[dst[e] >> 8], 1);
    __syncthreads();
    for (int i = t; i < NBKT; i += 512)
        if (hist[i]) base[i] = atomicAdd(&gcursor[i], hist[i]);
    __syncthreads();
    for (int e = lo + t; e < hi; e += 512) {
        int d = dst[e], s = src[e];
        int bk = d >> 8;
        int pos = base[bk] + atomicAdd(&cur[bk], 1);
        packed[pos] = ((d & 255) << 17) | s;
    }
}

// ---------------- csr_bucket: per-bucket node sort -> padded CSR + dinv ----------------

__global__ __launch_bounds__(256) void csr_bucket_kernel(const int* __restrict__ packed,
                                                         const int* __restrict__ gcursor,
                                                         int* __restrict__ rowptr,
                                                         int* __restrict__ rowend,
                                                         int* __restrict__ colx,
                                                         float* __restrict__ dinv) {
    __shared__ int hist[BWN], pfx[BWN], cur[BWN];
    int b = blockIdx.x, t = threadIdx.x;
    int nlo = b * BWN;
    int ncnt = NN - nlo; if (ncnt > BWN) ncnt = BWN;
    int ebeg = b * CAP, eend = gcursor[b];
    hist[t] = 0;
    __syncthreads();
    for (int e = ebeg + t; e < eend; e += 256) atomicAdd(&hist[packed[e] >> 17], 1);
    __syncthreads();
    int h = hist[t];
    pfx[t] = h;
    __syncthreads();
    for (int off = 1; off < 256; off <<= 1) {
        int u = (t >= off) ? pfx[t - off] : 0;
        __syncthreads();
        pfx[t] += u;
        __syncthreads();
    }
    int excl = pfx[t] - h;
    cur[t] = excl;
    int g = nlo + t;
    if (t < ncnt) {
        rowptr[g] = ebeg + excl;
        rowend[g] = ebeg + excl + h;
        dinv[g] = rsqrtf((float)(h + 1));  // +1 self-loop
    }
    __syncthreads();
    for (int e = ebeg + t; e < eend; e += 256) {
        int p = packed[e];
        int dl = p >> 17;
        int s = p & 0x1FFFF;
        int pos = ebeg + atomicAdd(&cur[dl], 1);
        colx[pos] = s;
    }
}

// ---------------- Layer 1 GEMM (MFMA bf16, reg-prefetch pipeline) ----------------
// hs = bf16((x @ W1) * dinv[row]); 4 waves, tile 64x64, BK=64, XOR-swizzled LDS.

__global__ __launch_bounds__(256) void gemm1_mfma(const float* __restrict__ x,
                                                  const ushort* __restrict__ w1t,
                                                  const float* __restrict__ dinv,
                                                  ushort* __restrict__ hs, int M) {
    __shared__ ushort As[64 * 64];
    __shared__ ushort Bs[64 * 64];
    char* Ab = (char*)As;
    char* Bb = (char*)Bs;

    int t = threadIdx.x;
    int row0 = blockIdx.x * 64;

    int srow = t >> 2;
    int klane = t & 3;
    int grow = row0 + srow; if (grow > M - 1) grow = M - 1;
    const float* xrow = x + (size_t)grow * IND;
    const char* wrow = (const char*)(w1t + (size_t)srow * IND);
    int swrow = srow * 128;
    int swx = (srow & 7) << 4;

    int l = t & 63;
    int w = t >> 6;
    int lr = l & 15;
    int lk = (l >> 4) * 16;
    int arow_b = (w * 16 + lr) * 128;
    int aswz = ((w * 16 + lr) & 7) << 4;

    f32x4 acc[4] = {};

    float4 rx[4]; uint2 rw[4];
#pragma unroll
    for (int i = 0; i < 4; ++i) {
        rx[i] = *(const float4*)(xrow + i * 16 + klane * 4);
        rw[i] = *(const uint2*)(wrow + i * 32 + klane * 8);
    }

    for (int k0 = 0; k0 < IND; k0 += 64) {
#pragma unroll
        for (int i = 0; i < 4; ++i) {
            int kb = i * 32 + klane * 8;
            uint2 pkd;
            pkd.x = pack2bf(rx[i].x, rx[i].y);
            pkd.y = pack2bf(rx[i].z, rx[i].w);
            *(uint2*)(Ab + swrow + (kb ^ swx)) = pkd;
            *(uint2*)(Bb + swrow + (kb ^ swx)) = rw[i];
        }
        __syncthreads();

        if (k0 + 64 < IND) {
#pragma unroll
            for (int i = 0; i < 4; ++i) {
                rx[i] = *(const float4*)(xrow + k0 + 64 + i * 16 + klane * 4);
                rw[i] = *(const uint2*)(wrow + (k0 + 64) * 2 + i * 32 + klane * 8);
            }
        }

        short8 a0 = *(const short8*)(Ab + arow_b + ((0 + lk) ^ aswz));
        short8 a1 = *(const short8*)(Ab + arow_b + ((64 + lk) ^ aswz));
#pragma unroll
        for (int ns = 0; ns < 4; ++ns) {
            int brow = ns * 16 + lr;
            int bswz = (brow & 7) << 4;
            short8 b0 = *(const short8*)(Bb + brow * 128 + ((0 + lk) ^ bswz));
            short8 b1 = *(const short8*)(Bb + brow * 128 + ((64 + lk) ^ bswz));
            acc[ns] = __builtin_amdgcn_mfma_f32_16x16x32_bf16(a0, b0, acc[ns], 0, 0, 0);
            acc[ns] = __builtin_amdgcn_mfma_f32_16x16x32_bf16(a1, b1, acc[ns], 0, 0, 0);
        }
        __syncthreads();
    }

    int rbase = row0 + w * 16 + (l >> 4) * 4;
    float dv[4];
#pragma unroll
    for (int j = 0; j < 4; ++j) dv[j] = (rbase + j < M) ? dinv[rbase + j] : 0.f;
#pragma unroll
    for (int ns = 0; ns < 4; ++ns) {
        int col = ns * 16 + lr;
#pragma unroll
        for (int j = 0; j < 4; ++j) {
            int row = rbase + j;
            if (row < M) hs[(size_t)row * HID + col] = (ushort)f2bf(acc[ns][j] * dv[j]);
        }
    }
}

// ---------------- agg1 + gemm2 fused ----------------
// half-wave per node: gather hs rows, finish h1 in regs (f32), then
// h2 = (h1 @ W2) * dinv via 32 broadcast-shuffles x LDS W2. Writes h2b only.

__global__ __launch_bounds__(256) void agg1_fused(const uint32* __restrict__ hs,
                                                  const int* __restrict__ rowptr,
                                                  const int* __restrict__ rowend,
                                                  const int* __restrict__ colx,
                                                  const float* __restrict__ dinv,
                                                  const float* __restrict__ b1,
                                                  const float* __restrict__ W2,
                                                  uint32* __restrict__ h2b) {
    __shared__ float w2s[64][42];
    int t = threadIdx.x;
    for (int i = t; i < HID * NC; i += 256) {
        int k = i / NC, c = i - k * NC;
        w2s[k][c] = W2[i];
    }
    __syncthreads();

    int node = (blockIdx.x * blockDim.x + t) >> 5;
    int l = t & 31;
    if (node >= NN) return;
    int beg = rowptr[node], end = rowend[node];
    uint32 u = hs[(size_t)node * 32 + l];  // self (already dinv-scaled)
    float a0 = bf_lo(u), a1 = bf_hi(u);
    int e = beg;
    int n8 = beg + ((end - beg) & ~7);
    for (; e < n8; e += 8) {
        int c[8];
#pragma unroll
        for (int j = 0; j < 8; ++j) c[j] = __builtin_nontemporal_load(&colx[e + j]);
        uint32 uu[8];
#pragma unroll
        for (int j = 0; j < 8; ++j) uu[j] = hs[(size_t)c[j] * 32 + l];
#pragma unroll
        for (int j = 0; j < 8; ++j) { a0 += bf_lo(uu[j]); a1 += bf_hi(uu[j]); }
    }
    for (; e < end; ++e) {
        uint32 ue = hs[(size_t)__builtin_nontemporal_load(&colx[e]) * 32 + l];
        a0 += bf_lo(ue); a1 += bf_hi(ue);
    }
    float d = dinv[node];
    float2 bb = *(const float2*)(b1 + 2 * l);
    float v0 = a0 * d + bb.x;
    float v1 = a1 * d + bb.y;
    v0 = v0 > 0.f ? v0 : 0.f;  // h1[2l]
    v1 = v1 > 0.f ? v1 : 0.f;  // h1[2l+1]

    // fused gemm2: lanes 0..19 each produce classes 2l, 2l+1
    float s0 = 0.f, s1 = 0.f;
#pragma unroll
    for (int k = 0; k < 32; ++k) {
        float u0 = __shfl(v0, k, 32);
        float u1 = __shfl(v1, k, 32);
        if (l < 20) {
            float2 wa = *(const float2*)&w2s[2 * k][2 * l];
            float2 wb = *(const float2*)&w2s[2 * k + 1][2 * l];
            s0 += u0 * wa.x + u1 * wb.x;
            s1 += u0 * wa.y + u1 * wb.y;
        }
    }
    if (l < 20)
        __builtin_nontemporal_store(pack2bf(s0 * d, s1 * d), &h2b[(size_t)node * 20 + l]);
}

// ---------------- agg2 + bias + log_softmax: half-wave per node ----------------

__global__ __launch_bounds__(256) void agg2_kernel(const uint32* __restrict__ h2b,
                                                   const int* __restrict__ rowptr,
                                                   const int* __restrict__ rowend,
                                                   const int* __restrict__ colx,
                                                   const float* __restrict__ dinv,
                                                   const float* __restrict__ b2,
                                                   float* __restrict__ out) {
    int node = (blockIdx.x * blockDim.x + threadIdx.x) >> 5;
    int l = threadIdx.x & 31;
    if (node >= NN) return;
    bool act = l < 20;
    int beg = rowptr[node], end = rowend[node];
    float a0 = 0.f, a1 = 0.f;
    if (act) {
        uint32 u = h2b[(size_t)node * 20 + l];
        a0 = bf_lo(u); a1 = bf_hi(u);
    }
    int e = beg;
    int n8 = beg + ((end - beg) & ~7);
    for (; e < n8; e += 8) {
        int c[8];
#pragma unroll
        for (int j = 0; j < 8; ++j) c[j] = __builtin_nontemporal_load(&colx[e + j]);
        if (act) {
            uint32 uu[8];
#pragma unroll
            for (int j = 0; j < 8; ++j) uu[j] = h2b[(size_t)c[j] * 20 + l];
#pragma unroll
            for (int j = 0; j < 8; ++j) { a0 += bf_lo(uu[j]); a1 += bf_hi(uu[j]); }
        }
    }
    for (; e < end; ++e) {
        int c = __builtin_nontemporal_load(&colx[e]);
        if (act) {
            uint32 ue = h2b[(size_t)c * 20 + l];
            a0 += bf_lo(ue); a1 += bf_hi(ue);
        }
    }

    float d = dinv[node];
    float v0 = -INFINITY, v1 = -INFINITY;
    if (act) {
        float2 bb = *(const float2*)(b2 + 2 * l);
        v0 = a0 * d + bb.x;
        v1 = a1 * d + bb.y;
    }
    float m = fmaxf(v0, v1);
#pragma unroll
    for (int off = 16; off; off >>= 1) m = fmaxf(m, __shfl_xor(m, off));
    float s = act ? (expf(v0 - m) + expf(v1 - m)) : 0.f;
#pragma unroll
    for (int off = 16; off; off >>= 1) s += __shfl_xor(s, off);
    if (act) {
        float ls = logf(s);
        __builtin_nontemporal_store(v0 - m - ls, &out[(size_t)node * NC + 2 * l]);
        __builtin_nontemporal_store(v1 - m - ls, &out[(size_t)node * NC + 2 * l + 1]);
    }
}

// ---------------- launch ----------------

extern "C" void kernel_launch(void* const* d_in, const int* in_sizes, int n_in,
                              void* d_out, int out_size, void* d_ws, size_t ws_size,
                              hipStream_t stream) {
    const float* x  = (const float*)d_in[0];
    const int* ei   = (const int*)d_in[1];
    const float* W1 = (const float*)d_in[2];
    const float* b1 = (const float*)d_in[3];
    const float* W2 = (const float*)d_in[4];
    const float* b2 = (const float*)d_in[5];
    float* out = (float*)d_out;

    const int E = in_sizes[1] / 2;
    const int* src = ei;
    const int* dst = ei + E;

    char* p = (char*)d_ws;
    size_t off = 0;
    auto carve = [&](size_t bytes) {
        void* q = p + off;
        off = (off + bytes + 255) & ~(size_t)255;
        return q;
    };
    int* gcursor  = (int*)carve((size_t)NBKT * 4);
    int* rowptr   = (int*)carve((size_t)NN * 4);
    int* rowend   = (int*)carve((size_t)NN * 4);
    float* dinv   = (float*)carve((size_t)NN * 4);
    ushort* w1t   = (ushort*)carve((size_t)IND * HID * 2);      // bf16 W1^T [64][512]
    ushort* hs    = (ushort*)carve((size_t)NN * HID * 2);       // bf16 [NN][64]
    uint32* h2b   = (uint32*)carve((size_t)NN * 20 * 4);        // bf16 pairs [NN][20]
    int* colx     = (int*)carve((size_t)NBKT * CAP * 4);        // padded CSR cols
    int* packed   = (int*)carve((size_t)NBKT * CAP * 4);        // padded bin staging

    wt_init_kernel<<<(IND * HID + 255) / 256, 256, 0, stream>>>(W1, w1t, gcursor);
    bin_kernel<<<NBIN_BLOCKS, 512, 0, stream>>>(src, dst, gcursor, packed, E);
    csr_bucket_kernel<<<NBKT, 256, 0, stream>>>(packed, gcursor, rowptr, rowend, colx, dinv);
    gemm1_mfma<<<(NN + 63) / 64, 256, 0, stream>>>(x, w1t, dinv, hs, NN);
    agg1_fused<<<(NN * 32 + 255) / 256, 256, 0, stream>>>((const uint32*)hs, rowptr, rowend, colx, dinv, b1, W2, h2b);
    agg2_kernel<<<(NN * 32 + 255) / 256, 256, 0, stream>>>(h2b, rowptr, rowend, colx, dinv, b2, out);
}

// Round 10
// 290.283 us; speedup vs baseline: 8.1777x; 1.0885x over previous
//
#include <hip/hip_runtime.h>
#include <hip/hip_bf16.h>
#include <cmath>

#define NN 100000
#define IND 512
#define HID 64
#define NC  40
#define BWN 256                      // nodes per bucket
#define NBKT ((NN + BWN - 1) / BWN)  // 391
#define CAP  12288                   // padded slots per bucket (avg 8184, +50%)
#define NBIN_BLOCKS 200

typedef unsigned int uint32;
typedef unsigned short ushort;
using short8 = __attribute__((ext_vector_type(8))) short;
using f32x4  = __attribute__((ext_vector_type(4))) float;

__device__ inline float bf_lo(uint32 u) { return __uint_as_float(u << 16); }
__device__ inline float bf_hi(uint32 u) { return __uint_as_float(u & 0xFFFF0000u); }
__device__ inline uint32 f2bf(float f) {
    uint32 u = __float_as_uint(f);
    return (u + 0x7FFFu + ((u >> 16) & 1u)) >> 16;  // RNE
}
__device__ inline uint32 pack2bf(float a, float b) { return f2bf(a) | (f2bf(b) << 16); }

// ---------------- wt_init: W1T + W2T bf16 transposes + gcursor init ----------------

__global__ __launch_bounds__(256) void wt_init_kernel(const float* __restrict__ W1,
                                                      const float* __restrict__ W2,
                                                      ushort* __restrict__ w1t,
                                                      ushort* __restrict__ w2t,
                                                      int* __restrict__ gcursor) {
    int id = blockIdx.x * blockDim.x + threadIdx.x;
    if (id < IND * HID) {
        int n = id & 63, k = id >> 6;
        w1t[(size_t)n * IND + k] = (ushort)f2bf(W1[(size_t)k * HID + n]);
    } else if (id < IND * HID + 48 * HID) {
        int id2 = id - IND * HID;
        int n = id2 >> 6, k = id2 & 63;
        w2t[id2] = (n < NC) ? (ushort)f2bf(W2[(size_t)k * NC + n]) : (ushort)0;
    }
    if (id < NBKT) gcursor[id] = id * CAP;
}

// ---------------- bin: bucket edges into padded staging ----------------

__global__ __launch_bounds__(512) void bin_kernel(const int* __restrict__ src,
                                                  const int* __restrict__ dst,
                                                  int* __restrict__ gcursor,
                                                  int* __restrict__ packed, int E) {
    __shared__ int hist[NBKT], base[NBKT], cur[NBKT];
    int b = blockIdx.x, t = threadIdx.x;
    int epb = (E + gridDim.x - 1) / gridDim.x;
    int lo = b * epb;
    int hi = lo + epb; if (hi > E) hi = E;
    for (int i = t; i < NBKT; i += 512) { hist[i] = 0; cur[i] = 0; }
    __syncthreads();
    for (int e = lo + t; e < hi; e += 512) atomicAdd(&hist[dst[e] >> 8], 1);
    __syncthreads();
    for (int i = t; i < NBKT; i += 512)
        if (hist[i]) base[i] = atomicAdd(&gcursor[i], hist[i]);
    __syncthreads();
    for (int e = lo + t; e < hi; e += 512) {
        int d = dst[e], s = src[e];
        int bk = d >> 8;
        int pos = base[bk] + atomicAdd(&cur[bk], 1);
        packed[pos] = ((d & 255) << 17) | s;
    }
}

// ---------------- csr_bucket: per-bucket node sort -> padded CSR + dinv ----------------

__global__ __launch_bounds__(256) void csr_bucket_kernel(const int* __restrict__ packed,
                                                         const int* __restrict__ gcursor,
                                                         int* __restrict__ rowptr,
                                                         int* __restrict__ rowend,
                                                         int* __restrict__ colx,
                                                         float* __restrict__ dinv) {
    __shared__ int hist[BWN], pfx[BWN], cur[BWN];
    int b = blockIdx.x, t = threadIdx.x;
    int nlo = b * BWN;
    int ncnt = NN - nlo; if (ncnt > BWN) ncnt = BWN;
    int ebeg = b * CAP, eend = gcursor[b];
    hist[t] = 0;
    __syncthreads();
    for (int e = ebeg + t; e < eend; e += 256) atomicAdd(&hist[packed[e] >> 17], 1);
    __syncthreads();
    int h = hist[t];
    pfx[t] = h;
    __syncthreads();
    for (int off = 1; off < 256; off <<= 1) {
        int u = (t >= off) ? pfx[t - off] : 0;
        __syncthreads();
        pfx[t] += u;
        __syncthreads();
    }
    int excl = pfx[t] - h;
    cur[t] = excl;
    int g = nlo + t;
    if (t < ncnt) {
        rowptr[g] = ebeg + excl;
        rowend[g] = ebeg + excl + h;
        dinv[g] = rsqrtf((float)(h + 1));  // +1 self-loop
    }
    __syncthreads();
    for (int e = ebeg + t; e < eend; e += 256) {
        int p = packed[e];
        int dl = p >> 17;
        int s = p & 0x1FFFF;
        int pos = ebeg + atomicAdd(&cur[dl], 1);
        colx[pos] = s;
    }
}

// ---------------- Layer 1 GEMM (MFMA bf16, reg-prefetch pipeline) ----------------

__global__ __launch_bounds__(256) void gemm1_mfma(const float* __restrict__ x,
                                                  const ushort* __restrict__ w1t,
                                                  const float* __restrict__ dinv,
                                                  ushort* __restrict__ hs, int M) {
    __shared__ ushort As[64 * 64];
    __shared__ ushort Bs[64 * 64];
    char* Ab = (char*)As;
    char* Bb = (char*)Bs;

    int t = threadIdx.x;
    int row0 = blockIdx.x * 64;

    int srow = t >> 2;
    int klane = t & 3;
    int grow = row0 + srow; if (grow > M - 1) grow = M - 1;
    const float* xrow = x + (size_t)grow * IND;
    const char* wrow = (const char*)(w1t + (size_t)srow * IND);
    int swrow = srow * 128;
    int swx = (srow & 7) << 4;

    int l = t & 63;
    int w = t >> 6;
    int lr = l & 15;
    int lk = (l >> 4) * 16;
    int arow_b = (w * 16 + lr) * 128;
    int aswz = ((w * 16 + lr) & 7) << 4;

    f32x4 acc[4] = {};

    float4 rx[4]; uint2 rw[4];
#pragma unroll
    for (int i = 0; i < 4; ++i) {
        rx[i] = *(const float4*)(xrow + i * 16 + klane * 4);
        rw[i] = *(const uint2*)(wrow + i * 32 + klane * 8);
    }

    for (int k0 = 0; k0 < IND; k0 += 64) {
#pragma unroll
        for (int i = 0; i < 4; ++i) {
            int kb = i * 32 + klane * 8;
            uint2 pkd;
            pkd.x = pack2bf(rx[i].x, rx[i].y);
            pkd.y = pack2bf(rx[i].z, rx[i].w);
            *(uint2*)(Ab + swrow + (kb ^ swx)) = pkd;
            *(uint2*)(Bb + swrow + (kb ^ swx)) = rw[i];
        }
        __syncthreads();

        if (k0 + 64 < IND) {
#pragma unroll
            for (int i = 0; i < 4; ++i) {
                rx[i] = *(const float4*)(xrow + k0 + 64 + i * 16 + klane * 4);
                rw[i] = *(const uint2*)(wrow + (k0 + 64) * 2 + i * 32 + klane * 8);
            }
        }

        short8 a0 = *(const short8*)(Ab + arow_b + ((0 + lk) ^ aswz));
        short8 a1 = *(const short8*)(Ab + arow_b + ((64 + lk) ^ aswz));
#pragma unroll
        for (int ns = 0; ns < 4; ++ns) {
            int brow = ns * 16 + lr;
            int bswz = (brow & 7) << 4;
            short8 b0 = *(const short8*)(Bb + brow * 128 + ((0 + lk) ^ bswz));
            short8 b1 = *(const short8*)(Bb + brow * 128 + ((64 + lk) ^ bswz));
            acc[ns] = __builtin_amdgcn_mfma_f32_16x16x32_bf16(a0, b0, acc[ns], 0, 0, 0);
            acc[ns] = __builtin_amdgcn_mfma_f32_16x16x32_bf16(a1, b1, acc[ns], 0, 0, 0);
        }
        __syncthreads();
    }

    int rbase = row0 + w * 16 + (l >> 4) * 4;
    float dv[4];
#pragma unroll
    for (int j = 0; j < 4; ++j) dv[j] = (rbase + j < M) ? dinv[rbase + j] : 0.f;
#pragma unroll
    for (int ns = 0; ns < 4; ++ns) {
        int col = ns * 16 + lr;
#pragma unroll
        for (int j = 0; j < 4; ++j) {
            int row = rbase + j;
            if (row < M) hs[(size_t)row * HID + col] = (ushort)f2bf(acc[ns][j] * dv[j]);
        }
    }
}

// ---------------- agg1: half-wave per node, bf16 gather, bf16 h1 out ----------------

__global__ __launch_bounds__(256) void agg1_kernel(const uint32* __restrict__ hs,
                                                   const int* __restrict__ rowptr,
                                                   const int* __restrict__ rowend,
                                                   const int* __restrict__ colx,
                                                   const float* __restrict__ dinv,
                                                   const float* __restrict__ b1,
                                                   uint32* __restrict__ h1) {
    int node = (blockIdx.x * blockDim.x + threadIdx.x) >> 5;
    int l = threadIdx.x & 31;
    if (node >= NN) return;
    int beg = rowptr[node], end = rowend[node];
    uint32 u = hs[(size_t)node * 32 + l];  // self (already dinv-scaled)
    float a0 = bf_lo(u), a1 = bf_hi(u);
    int e = beg;
    int n8 = beg + ((end - beg) & ~7);
    for (; e < n8; e += 8) {
        int c[8];
#pragma unroll
        for (int j = 0; j < 8; ++j) c[j] = __builtin_nontemporal_load(&colx[e + j]);
        uint32 uu[8];
#pragma unroll
        for (int j = 0; j < 8; ++j) uu[j] = hs[(size_t)c[j] * 32 + l];
#pragma unroll
        for (int j = 0; j < 8; ++j) { a0 += bf_lo(uu[j]); a1 += bf_hi(uu[j]); }
    }
    for (; e < end; ++e) {
        uint32 ue = hs[(size_t)__builtin_nontemporal_load(&colx[e]) * 32 + l];
        a0 += bf_lo(ue); a1 += bf_hi(ue);
    }
    float d = dinv[node];
    float2 bb = *(const float2*)(b1 + 2 * l);
    float v0 = a0 * d + bb.x;
    float v1 = a1 * d + bb.y;
    v0 = v0 > 0.f ? v0 : 0.f;
    v1 = v1 > 0.f ? v1 : 0.f;
    __builtin_nontemporal_store(pack2bf(v0, v1), &h1[(size_t)node * 32 + l]);
}

// ---------------- Layer 2 GEMM (MFMA, LDS-free): h2b = bf16((h1 @ W2) * dinv) ----------------

__global__ __launch_bounds__(256) void gemm2_mfma(const ushort* __restrict__ h1,
                                                  const ushort* __restrict__ w2t,
                                                  const float* __restrict__ dinv,
                                                  ushort* __restrict__ h2b, int M) {
    int t = threadIdx.x;
    int w = t >> 6, l = t & 63;
    int lr = l & 15, lh = l >> 4;
    int row0 = blockIdx.x * 64 + w * 16;
    int arow = row0 + lr; if (arow > M - 1) arow = M - 1;
    const ushort* hrow = h1 + (size_t)arow * HID;

    f32x4 acc[3] = {};
#pragma unroll
    for (int ks = 0; ks < 2; ++ks) {
        short8 a = *(const short8*)(hrow + ks * 32 + lh * 8);
#pragma unroll
        for (int ns = 0; ns < 3; ++ns) {
            short8 b = *(const short8*)(w2t + (size_t)(ns * 16 + lr) * HID + ks * 32 + lh * 8);
            acc[ns] = __builtin_amdgcn_mfma_f32_16x16x32_bf16(a, b, acc[ns], 0, 0, 0);
        }
    }

    int rbase = row0 + lh * 4;
    float dv[4];
#pragma unroll
    for (int j = 0; j < 4; ++j) dv[j] = (rbase + j < M) ? dinv[rbase + j] : 0.f;
#pragma unroll
    for (int ns = 0; ns < 3; ++ns) {
        int col = ns * 16 + lr;
        if (col < NC) {
#pragma unroll
            for (int j = 0; j < 4; ++j) {
                int row = rbase + j;
                if (row < M) h2b[(size_t)row * NC + col] = (ushort)f2bf(acc[ns][j] * dv[j]);
            }
        }
    }
}

// ---------------- agg2 + bias + log_softmax: half-wave per node ----------------

__global__ __launch_bounds__(256) void agg2_kernel(const uint32* __restrict__ h2b,
                                                   const int* __restrict__ rowptr,
                                                   const int* __restrict__ rowend,
                                                   const int* __restrict__ colx,
                                                   const float* __restrict__ dinv,
                                                   const float* __restrict__ b2,
                                                   float* __restrict__ out) {
    int node = (blockIdx.x * blockDim.x + threadIdx.x) >> 5;
    int l = threadIdx.x & 31;
    if (node >= NN) return;
    bool act = l < 20;
    int beg = rowptr[node], end = rowend[node];
    float a0 = 0.f, a1 = 0.f;
    if (act) {
        uint32 u = h2b[(size_t)node * 20 + l];
        a0 = bf_lo(u); a1 = bf_hi(u);
    }
    int e = beg;
    int n8 = beg + ((end - beg) & ~7);
    for (; e < n8; e += 8) {
        int c[8];
#pragma unroll
        for (int j = 0; j < 8; ++j) c[j] = __builtin_nontemporal_load(&colx[e + j]);
        if (act) {
            uint32 uu[8];
#pragma unroll
            for (int j = 0; j < 8; ++j) uu[j] = h2b[(size_t)c[j] * 20 + l];
#pragma unroll
            for (int j = 0; j < 8; ++j) { a0 += bf_lo(uu[j]); a1 += bf_hi(uu[j]); }
        }
    }
    for (; e < end; ++e) {
        int c = __builtin_nontemporal_load(&colx[e]);
        if (act) {
            uint32 ue = h2b[(size_t)c * 20 + l];
            a0 += bf_lo(ue); a1 += bf_hi(ue);
        }
    }

    float d = dinv[node];
    float v0 = -INFINITY, v1 = -INFINITY;
    if (act) {
        float2 bb = *(const float2*)(b2 + 2 * l);
        v0 = a0 * d + bb.x;
        v1 = a1 * d + bb.y;
    }
    float m = fmaxf(v0, v1);
#pragma unroll
    for (int off = 16; off; off >>= 1) m = fmaxf(m, __shfl_xor(m, off));
    float s = act ? (expf(v0 - m) + expf(v1 - m)) : 0.f;
#pragma unroll
    for (int off = 16; off; off >>= 1) s += __shfl_xor(s, off);
    if (act) {
        float ls = logf(s);
        __builtin_nontemporal_store(v0 - m - ls, &out[(size_t)node * NC + 2 * l]);
        __builtin_nontemporal_store(v1 - m - ls, &out[(size_t)node * NC + 2 * l + 1]);
    }
}

// ---------------- launch ----------------

extern "C" void kernel_launch(void* const* d_in, const int* in_sizes, int n_in,
                              void* d_out, int out_size, void* d_ws, size_t ws_size,
                              hipStream_t stream) {
    const float* x  = (const float*)d_in[0];
    const int* ei   = (const int*)d_in[1];
    const float* W1 = (const float*)d_in[2];
    const float* b1 = (const float*)d_in[3];
    const float* W2 = (const float*)d_in[4];
    const float* b2 = (const float*)d_in[5];
    float* out = (float*)d_out;

    const int E = in_sizes[1] / 2;
    const int* src = ei;
    const int* dst = ei + E;

    char* p = (char*)d_ws;
    size_t off = 0;
    auto carve = [&](size_t bytes) {
        void* q = p + off;
        off = (off + bytes + 255) & ~(size_t)255;
        return q;
    };
    int* gcursor  = (int*)carve((size_t)NBKT * 4);
    int* rowptr   = (int*)carve((size_t)NN * 4);
    int* rowend   = (int*)carve((size_t)NN * 4);
    float* dinv   = (float*)carve((size_t)NN * 4);
    ushort* w1t   = (ushort*)carve((size_t)IND * HID * 2);      // bf16 W1^T [64][512]
    ushort* w2t   = (ushort*)carve((size_t)48 * HID * 2);       // bf16 W2^T [48][64], padded
    ushort* hs    = (ushort*)carve((size_t)NN * HID * 2);       // bf16 [NN][64]
    uint32* h1    = (uint32*)carve((size_t)NN * 32 * 4);        // bf16 pairs [NN][32]
    ushort* h2b   = (ushort*)carve((size_t)NN * NC * 2);        // bf16 [NN][40]
    int* colx     = (int*)carve((size_t)NBKT * CAP * 4);        // padded CSR cols
    int* packed   = (int*)carve((size_t)NBKT * CAP * 4);        // padded bin staging

    wt_init_kernel<<<(IND * HID + 48 * HID + 255) / 256, 256, 0, stream>>>(W1, W2, w1t, w2t, gcursor);
    bin_kernel<<<NBIN_BLOCKS, 512, 0, stream>>>(src, dst, gcursor, packed, E);
    csr_bucket_kernel<<<NBKT, 256, 0, stream>>>(packed, gcursor, rowptr, rowend, colx, dinv);
    gemm1_mfma<<<(NN + 63) / 64, 256, 0, stream>>>(x, w1t, dinv, hs, NN);
    agg1_kernel<<<(NN * 32 + 255) / 256, 256, 0, stream>>>((const uint32*)hs, rowptr, rowend, colx, dinv, b1, h1);
    gemm2_mfma<<<(NN + 63) / 64, 256, 0, stream>>>((const ushort*)h1, w2t, dinv, h2b, NN);
    agg2_kernel<<<(NN * 32 + 255) / 256, 256, 0, stream>>>((const uint32*)h2b, rowptr, rowend, colx, dinv, b2, out);
}